// Round 3
// baseline (483.747 us; speedup 1.0000x reference)
//
#include <hip/hip_runtime.h>
#include <hip/hip_fp16.h>
#include <math.h>

constexpr int NTOK = 524288;   // T
constexpr int NB   = 4096;     // B
constexpr int H    = 512;
constexpr float EPS = 1e-5f;

typedef _Float16 half8 __attribute__((ext_vector_type(8)));
typedef float f32x4 __attribute__((ext_vector_type(4)));
struct h4 { __half2 a, b; };   // 8 bytes = 4 halves

// ---------------------------------------------------------------------------
// K0 (prep): W1 fp32->fp16 (blocks 0..255), segment-bounds scan (blocks
// 256..2303), zero the epilogue spin counters and loss accumulator.
// emb is NOT converted any more -- the gather reads fp32 directly.
// ---------------------------------------------------------------------------
__global__ __launch_bounds__(256) void k_prep(
    const float* __restrict__ W1, h4* __restrict__ W1h,
    const int* __restrict__ seg, int* __restrict__ starts,
    unsigned* __restrict__ ctr, float* __restrict__ out) {
  const int bid = blockIdx.x;
  const int tid = threadIdx.x;
  if (bid == 0 && tid < 2) { ctr[tid] = 0u; if (tid == 0) out[0] = 0.f; }
  if (bid < 256) {
    const int i = bid * 256 + tid;           // 65536 float4s of W1
    f32x4 v = *((const f32x4*)W1 + i);
    h4 o;
    o.a = __floats2half2_rn(v[0], v[1]);
    o.b = __floats2half2_rn(v[2], v[3]);
    W1h[i] = o;
  } else {
    const int i = (bid - 256) * 256 + tid;   // 524288 tokens
    const int cur = seg[i];
    const int prev = (i == 0) ? -1 : seg[i - 1];
    for (int b = prev + 1; b <= cur; ++b) starts[b] = i;
    if (i == NTOK - 1) {
      for (int b = cur + 1; b <= NB; ++b) starts[b] = NTOK;
    }
  }
}

// ---------------------------------------------------------------------------
// K1: fused gather + segment mean, DIRECT from fp32 emb (2 KB rows).
// 256 threads = 4 token-groups x 64 lanes; each lane owns two float4s:
// cols [4*lane, 4*lane+4) and [256+4*lane, 256+4*lane+4)  (both loads are
// fully coalesced 1 KB wave segments).  fp32 accum, fp16 bow out.
// Unique footprint 204.8 MB < 256 MB L3; 5.24x token reuse -> re-reads L3-hit.
// ---------------------------------------------------------------------------
__global__ __launch_bounds__(256) void k_gather_mean(
    const int* __restrict__ tokens, const int* __restrict__ starts,
    const float* __restrict__ emb, h4* __restrict__ bow_h) {
  const int b = blockIdx.x;
  const int start = starts[b];
  const int end = starts[b + 1];

  const int tid = threadIdx.x;
  const int lane = tid & 63;
  const int g = tid >> 6;
  const f32x4* e4 = (const f32x4*)emb;

  float acc[8] = {};
  int i = start + g;
  for (; i + 12 < end; i += 16) {
    const size_t r0 = (size_t)tokens[i]      * 128 + lane;
    const size_t r1 = (size_t)tokens[i + 4]  * 128 + lane;
    const size_t r2 = (size_t)tokens[i + 8]  * 128 + lane;
    const size_t r3 = (size_t)tokens[i + 12] * 128 + lane;
    f32x4 a0 = e4[r0], c0 = e4[r0 + 64];
    f32x4 a1 = e4[r1], c1 = e4[r1 + 64];
    f32x4 a2 = e4[r2], c2 = e4[r2 + 64];
    f32x4 a3 = e4[r3], c3 = e4[r3 + 64];
#pragma unroll
    for (int j = 0; j < 4; ++j) {
      acc[j]     += a0[j] + a1[j] + a2[j] + a3[j];
      acc[4 + j] += c0[j] + c1[j] + c2[j] + c3[j];
    }
  }
  for (; i < end; i += 4) {
    const size_t r0 = (size_t)tokens[i] * 128 + lane;
    f32x4 a0 = e4[r0], c0 = e4[r0 + 64];
#pragma unroll
    for (int j = 0; j < 4; ++j) { acc[j] += a0[j]; acc[4 + j] += c0[j]; }
  }

  __shared__ float part[3][64][9];   // +1 pad breaks bank aliasing
  if (g > 0) {
#pragma unroll
    for (int j = 0; j < 8; ++j) part[g - 1][lane][j] = acc[j];
  }
  __syncthreads();
  if (g == 0) {
    const int cnt = end - start;
    const float s = 1.0f / (float)(cnt > 0 ? cnt : 1);
    float v[8];
#pragma unroll
    for (int j = 0; j < 8; ++j)
      v[j] = (acc[j] + part[0][lane][j] + part[1][lane][j] + part[2][lane][j]) * s;
    h4 lo, hi;
    lo.a = __floats2half2_rn(v[0], v[1]); lo.b = __floats2half2_rn(v[2], v[3]);
    hi.a = __floats2half2_rn(v[4], v[5]); hi.b = __floats2half2_rn(v[6], v[7]);
    // row b is 128 h4s; lane -> cols [4*lane,+4), 64+lane -> cols [256+4*lane,+4)
    bow_h[(size_t)b * 128 + lane]      = lo;
    bow_h[(size_t)b * 128 + 64 + lane] = hi;
  }
}

// ---------------------------------------------------------------------------
// K2: z = bow @ W1^T + b1 via fp16 MFMA, fp32 accum.
// Per wave: 16 m-rows x 64 n-cols (4 frags), K=512 fully in-register loop.
// No LDS: A/B frag loads are 16 B/lane straight from L2.
// ---------------------------------------------------------------------------
__global__ __launch_bounds__(256) void k_gemm_mfma(
    const _Float16* __restrict__ A,   // bow_h [NB][H]
    const _Float16* __restrict__ Bw,  // W1h   [H][H]
    const float* __restrict__ b1, float* __restrict__ C) {
  const int tid = threadIdx.x;
  const int lane = tid & 63;
  const int gw = blockIdx.x * 4 + (tid >> 6);   // 2048 waves total
  const int m0 = (gw >> 3) * 16;                // 256 m-tiles
  const int n0 = (gw & 7) * 64;                 // 8 n-groups
  const int l15 = lane & 15, quad = lane >> 4;

  f32x4 acc0 = {}, acc1 = {}, acc2 = {}, acc3 = {};
  const _Float16* ap = A + (size_t)(m0 + l15) * H + quad * 8;
  const _Float16* bp = Bw + (size_t)(n0 + l15) * H + quad * 8;

#pragma unroll
  for (int k = 0; k < H; k += 32) {
    half8 af  = *(const half8*)(ap + k);
    half8 bf0 = *(const half8*)(bp + k);
    half8 bf1 = *(const half8*)(bp + 16 * H + k);
    half8 bf2 = *(const half8*)(bp + 32 * H + k);
    half8 bf3 = *(const half8*)(bp + 48 * H + k);
    acc0 = __builtin_amdgcn_mfma_f32_16x16x32_f16(af, bf0, acc0, 0, 0, 0);
    acc1 = __builtin_amdgcn_mfma_f32_16x16x32_f16(af, bf1, acc1, 0, 0, 0);
    acc2 = __builtin_amdgcn_mfma_f32_16x16x32_f16(af, bf2, acc2, 0, 0, 0);
    acc3 = __builtin_amdgcn_mfma_f32_16x16x32_f16(af, bf3, acc3, 0, 0, 0);
  }

  const float bn0v = b1[n0 + l15];
  const float bn1v = b1[n0 + 16 + l15];
  const float bn2v = b1[n0 + 32 + l15];
  const float bn3v = b1[n0 + 48 + l15];
  float* crow = C + (size_t)(m0 + quad * 4) * H + n0 + l15;
#pragma unroll
  for (int r = 0; r < 4; ++r) {
    crow[(size_t)r * H]      = acc0[r] + bn0v;
    crow[(size_t)r * H + 16] = acc1[r] + bn1v;
    crow[(size_t)r * H + 32] = acc2[r] + bn2v;
    crow[(size_t)r * H + 48] = acc3[r] + bn3v;
  }
}

// ---------------------------------------------------------------------------
// K3 (epilogue, single launch): colstats -> BN finalize -> bn_dot+loss with
// two device-scope spin barriers.  Grid is EXACTLY 256 blocks x 256 threads
// (1 block/CU, tiny LDS/VGPR) -> all blocks co-resident, spin is safe.
// Unsigned counter compares: a poisoned counter can never spin forever.
// ---------------------------------------------------------------------------
__global__ __launch_bounds__(256) void k_epilogue(
    const float* __restrict__ z,
    const float* __restrict__ gamma, const float* __restrict__ beta,
    const float* __restrict__ w2, const float* __restrict__ b2,
    const float* __restrict__ t,
    float* __restrict__ ps, float* __restrict__ pss,
    unsigned* __restrict__ ctr,
    float* __restrict__ scale, float* __restrict__ shift,
    float* __restrict__ out) {
  const int blk = blockIdx.x;   // 0..255
  const int tid = threadIdx.x;  // 0..255
  const int w = tid >> 6, lane = tid & 63;

  // ---- Phase A: partial column sums/sumsq over rows [blk*16, +16)
  {
    const int c0 = tid * 2;
    const int r0 = blk * 16;
    float s0 = 0, s1 = 0, q0 = 0, q1 = 0;
#pragma unroll
    for (int r = 0; r < 16; ++r) {
      float2 v = *(const float2*)&z[(size_t)(r0 + r) * H + c0];
      s0 += v.x; s1 += v.y;
      q0 += v.x * v.x; q1 += v.y * v.y;
    }
    ps[blk * H + c0] = s0;  ps[blk * H + c0 + 1] = s1;
    pss[blk * H + c0] = q0; pss[blk * H + c0 + 1] = q1;
  }
  __threadfence();
  __syncthreads();
  if (tid == 0) {
    __hip_atomic_fetch_add(ctr, 1u, __ATOMIC_ACQ_REL, __HIP_MEMORY_SCOPE_AGENT);
    while (__hip_atomic_load(ctr, __ATOMIC_ACQUIRE, __HIP_MEMORY_SCOPE_AGENT) < 256u)
      __builtin_amdgcn_s_sleep(8);
  }
  __syncthreads();

  // ---- Phase B: this block reduces cols 2*blk, 2*blk+1 over 256 partials
  {
    float2 pv = *(const float2*)&ps[(size_t)tid * H + 2 * blk];
    float2 qv = *(const float2*)&pss[(size_t)tid * H + 2 * blk];
    float v0 = pv.x, v1 = pv.y, v2 = qv.x, v3 = qv.y;
#pragma unroll
    for (int off = 32; off > 0; off >>= 1) {
      v0 += __shfl_down(v0, off, 64); v1 += __shfl_down(v1, off, 64);
      v2 += __shfl_down(v2, off, 64); v3 += __shfl_down(v3, off, 64);
    }
    __shared__ float red[4][4];
    if (lane == 0) { red[w][0] = v0; red[w][1] = v1; red[w][2] = v2; red[w][3] = v3; }
    __syncthreads();
    if (tid == 0) {
      const float s0 = red[0][0] + red[1][0] + red[2][0] + red[3][0];
      const float s1 = red[0][1] + red[1][1] + red[2][1] + red[3][1];
      const float q0 = red[0][2] + red[1][2] + red[2][2] + red[3][2];
      const float q1 = red[0][3] + red[1][3] + red[2][3] + red[3][3];
      const int c = 2 * blk;
      const float mu0 = s0 * (1.0f / NB), mu1 = s1 * (1.0f / NB);
      const float sc0 = rsqrtf(q0 * (1.0f / NB) - mu0 * mu0 + EPS) * gamma[c];
      const float sc1 = rsqrtf(q1 * (1.0f / NB) - mu1 * mu1 + EPS) * gamma[c + 1];
      scale[c] = sc0;     shift[c] = beta[c] - mu0 * sc0;
      scale[c + 1] = sc1; shift[c + 1] = beta[c + 1] - mu1 * sc1;
    }
  }
  __threadfence();
  __syncthreads();
  if (tid == 0) {
    __hip_atomic_fetch_add(ctr + 1, 1u, __ATOMIC_ACQ_REL, __HIP_MEMORY_SCOPE_AGENT);
    while (__hip_atomic_load(ctr + 1, __ATOMIC_ACQUIRE, __HIP_MEMORY_SCOPE_AGENT) < 256u)
      __builtin_amdgcn_s_sleep(8);
  }
  __syncthreads();

  // ---- Phase C: BN + ReLU + dot(w2) + loss for rows [blk*16, +16)
  {
    __shared__ __align__(16) float sc_s[H], sh_s[H];
    sc_s[tid] = scale[tid]; sc_s[256 + tid] = scale[256 + tid];
    sh_s[tid] = shift[tid]; sh_s[256 + tid] = shift[256 + tid];
    __syncthreads();
    float lsum = 0.f;
#pragma unroll
    for (int rr = 0; rr < 4; ++rr) {
      const int row = blk * 16 + w * 4 + rr;
      const float4* z4 = (const float4*)(z + (size_t)row * H);
      float acc = 0.f;
#pragma unroll
      for (int ii = 0; ii < 2; ++ii) {
        const int idx = lane + ii * 64;
        float4 zv = z4[idx];
        float4 sc = *(const float4*)&sc_s[idx * 4];
        float4 sh = *(const float4*)&sh_s[idx * 4];
        float4 wv = ((const float4*)w2)[idx];
        acc += fmaxf(zv.x * sc.x + sh.x, 0.f) * wv.x
             + fmaxf(zv.y * sc.y + sh.y, 0.f) * wv.y
             + fmaxf(zv.z * sc.z + sh.z, 0.f) * wv.z
             + fmaxf(zv.w * sc.w + sh.w, 0.f) * wv.w;
      }
#pragma unroll
      for (int off = 32; off > 0; off >>= 1) acc += __shfl_down(acc, off, 64);
      if (lane == 0) {
        const float logit = acc + b2[0];
        out[1 + row] = logit;
        const float sp = fmaxf(logit, 0.f) + log1pf(expf(-fabsf(logit)));
        lsum += sp - t[row] * logit;
      }
    }
    __shared__ float ls[4];
    if (lane == 0) ls[w] = lsum;
    __syncthreads();
    if (tid == 0) atomicAdd(out, (ls[0] + ls[1] + ls[2] + ls[3]) * (1.0f / NB));
  }
}

// ---------------------------------------------------------------------------
extern "C" void kernel_launch(void* const* d_in, const int* in_sizes, int n_in,
                              void* d_out, int out_size, void* d_ws, size_t ws_size,
                              hipStream_t stream) {
  const int*   tokens = (const int*)d_in[0];
  const int*   seg    = (const int*)d_in[1];
  const float* t      = (const float*)d_in[2];
  const float* emb    = (const float*)d_in[3];
  const float* W1     = (const float*)d_in[4];
  const float* b1     = (const float*)d_in[5];
  const float* gamma  = (const float*)d_in[6];
  const float* beta   = (const float*)d_in[7];
  const float* w2     = (const float*)d_in[8];
  const float* b2     = (const float*)d_in[9];
  float* out = (float*)d_out;

  // workspace layout (bytes)
  char* wsb = (char*)d_ws;
  _Float16* W1h   = (_Float16*)wsb;                // 512*512*2   =    524,288
  h4*       bow_h = (h4*)(wsb + 524288);           // 4096*512*2  =  4,194,304
  float*    z     = (float*)(wsb + 4718592);       // 4096*512*4  =  8,388,608
  float*    ps    = (float*)(wsb + 13107200);      // 256*512*4   =    524,288
  float*    pss   = ps + 256 * H;                  //                  524,288
  float*    scale = pss + 256 * H;                 //                    2,048
  float*    shift = scale + H;                     //                    2,048
  int*      starts = (int*)(wsb + 14159872);       // (NB+1)*4    =     16,388
  unsigned* ctr    = (unsigned*)(wsb + 14180352);  //                        8

  k_prep<<<2304, 256, 0, stream>>>(W1, (h4*)W1h, seg, starts, ctr, out);
  k_gather_mean<<<NB, 256, 0, stream>>>(tokens, starts, emb, bow_h);
  k_gemm_mfma<<<512, 256, 0, stream>>>((const _Float16*)bow_h, W1h, b1, z);
  k_epilogue<<<256, 256, 0, stream>>>(z, gamma, beta, w2, b2, t,
                                      ps, pss, ctr, scale, shift, out);
}

// Round 4
// 426.336 us; speedup vs baseline: 1.1347x; 1.1347x over previous
//
#include <hip/hip_runtime.h>
#include <hip/hip_fp16.h>
#include <math.h>

constexpr int NTOK = 524288;   // T
constexpr int NB   = 4096;     // B
constexpr int H    = 512;
constexpr float EPS = 1e-5f;

typedef _Float16 half8 __attribute__((ext_vector_type(8)));
typedef float f32x4 __attribute__((ext_vector_type(4)));
struct h4 { __half2 a, b; };   // 8 bytes = 4 halves

// ---------------------------------------------------------------------------
// K0: fp32 -> fp16 convert, emb (blocks 0..49999) + W1 (blocks 50000..50255).
// Plain loads (NT hint measured neutral-to-negative in R2).
// ---------------------------------------------------------------------------
__global__ __launch_bounds__(256) void k_convert(
    const float* __restrict__ emb, h4* __restrict__ embh,
    const float* __restrict__ W1, h4* __restrict__ W1h) {
  const size_t bid = blockIdx.x;
  if (bid < 50000) {
    size_t i = bid * 256 + threadIdx.x;
    f32x4 v = *((const f32x4*)emb + i);
    h4 o;
    o.a = __floats2half2_rn(v[0], v[1]);
    o.b = __floats2half2_rn(v[2], v[3]);
    embh[i] = o;
  } else {
    size_t i = (bid - 50000) * 256 + threadIdx.x;
    f32x4 v = *((const f32x4*)W1 + i);
    h4 o;
    o.a = __floats2half2_rn(v[0], v[1]);
    o.b = __floats2half2_rn(v[2], v[3]);
    W1h[i] = o;
  }
}

// ---------------------------------------------------------------------------
// K1a: segment boundary scan. starts[b] = lower_bound(seg, b); starts[NB]=T.
// ---------------------------------------------------------------------------
__global__ __launch_bounds__(256) void k_bounds(
    const int* __restrict__ seg, int* __restrict__ starts) {
  const int i = blockIdx.x * 256 + threadIdx.x;
  const int cur = seg[i];
  const int prev = (i == 0) ? -1 : seg[i - 1];
  for (int b = prev + 1; b <= cur; ++b) starts[b] = i;
  if (i == NTOK - 1) {
    for (int b = cur + 1; b <= NB; ++b) starts[b] = NTOK;
  }
}

// ---------------------------------------------------------------------------
// K1b: fused gather + segment mean (fp16 table, fp32 accum, fp16 bow out).
// 256 threads = 4 token-groups x 64 lanes; each lane owns 16 B (8 cols).
// 8-deep unroll -> 8 outstanding 16B loads/lane (R3 showed the gather regime
// is latency-bound, not BW-bound: 37% HBM peak, VALUBusy 5%).
// ---------------------------------------------------------------------------
__global__ __launch_bounds__(256) void k_gather_mean(
    const int* __restrict__ tokens, const int* __restrict__ starts,
    const half8* __restrict__ embh, half8* __restrict__ bow_h) {
  const int b = blockIdx.x;
  const int start = starts[b];
  const int end = starts[b + 1];

  const int tid = threadIdx.x;
  const int lane = tid & 63;
  const int g = tid >> 6;

  float acc[8] = {};
  int i = start + g;
  // 8 rows in flight per wave (rows i, i+4, ..., i+28)
  for (; i + 28 < end; i += 32) {
    half8 v0 = embh[(size_t)tokens[i]      * 64 + lane];
    half8 v1 = embh[(size_t)tokens[i + 4]  * 64 + lane];
    half8 v2 = embh[(size_t)tokens[i + 8]  * 64 + lane];
    half8 v3 = embh[(size_t)tokens[i + 12] * 64 + lane];
    half8 v4 = embh[(size_t)tokens[i + 16] * 64 + lane];
    half8 v5 = embh[(size_t)tokens[i + 20] * 64 + lane];
    half8 v6 = embh[(size_t)tokens[i + 24] * 64 + lane];
    half8 v7 = embh[(size_t)tokens[i + 28] * 64 + lane];
#pragma unroll
    for (int j = 0; j < 8; ++j)
      acc[j] += ((float)v0[j] + (float)v1[j]) + ((float)v2[j] + (float)v3[j])
              + ((float)v4[j] + (float)v5[j]) + ((float)v6[j] + (float)v7[j]);
  }
  for (; i < end; i += 4) {
    half8 v0 = embh[(size_t)tokens[i] * 64 + lane];
#pragma unroll
    for (int j = 0; j < 8; ++j) acc[j] += (float)v0[j];
  }

  __shared__ float part[3][64][9];   // +1 pad breaks bank aliasing
  if (g > 0) {
#pragma unroll
    for (int j = 0; j < 8; ++j) part[g - 1][lane][j] = acc[j];
  }
  __syncthreads();
  if (g == 0) {
    const int cnt = end - start;
    const float s = 1.0f / (float)(cnt > 0 ? cnt : 1);
    half8 o;
#pragma unroll
    for (int j = 0; j < 8; ++j) {
      float v = acc[j] + part[0][lane][j] + part[1][lane][j] + part[2][lane][j];
      o[j] = (_Float16)(v * s);
    }
    bow_h[(size_t)b * 64 + lane] = o;
  }
}

// ---------------------------------------------------------------------------
// K2: z = bow @ W1^T + b1 via fp16 MFMA, fp32 accum.
// Per wave: 16 m-rows x 64 n-cols (4 frags), K=512 fully in-register loop.
// ---------------------------------------------------------------------------
__global__ __launch_bounds__(256) void k_gemm_mfma(
    const _Float16* __restrict__ A,   // bow_h [NB][H]
    const _Float16* __restrict__ Bw,  // W1h   [H][H]
    const float* __restrict__ b1, float* __restrict__ C) {
  const int tid = threadIdx.x;
  const int lane = tid & 63;
  const int gw = blockIdx.x * 4 + (tid >> 6);   // 2048 waves total
  const int m0 = (gw >> 3) * 16;                // 256 m-tiles
  const int n0 = (gw & 7) * 64;                 // 8 n-groups
  const int l15 = lane & 15, quad = lane >> 4;

  f32x4 acc0 = {}, acc1 = {}, acc2 = {}, acc3 = {};
  const _Float16* ap = A + (size_t)(m0 + l15) * H + quad * 8;
  const _Float16* bp = Bw + (size_t)(n0 + l15) * H + quad * 8;

#pragma unroll
  for (int k = 0; k < H; k += 32) {
    half8 af  = *(const half8*)(ap + k);
    half8 bf0 = *(const half8*)(bp + k);
    half8 bf1 = *(const half8*)(bp + 16 * H + k);
    half8 bf2 = *(const half8*)(bp + 32 * H + k);
    half8 bf3 = *(const half8*)(bp + 48 * H + k);
    acc0 = __builtin_amdgcn_mfma_f32_16x16x32_f16(af, bf0, acc0, 0, 0, 0);
    acc1 = __builtin_amdgcn_mfma_f32_16x16x32_f16(af, bf1, acc1, 0, 0, 0);
    acc2 = __builtin_amdgcn_mfma_f32_16x16x32_f16(af, bf2, acc2, 0, 0, 0);
    acc3 = __builtin_amdgcn_mfma_f32_16x16x32_f16(af, bf3, acc3, 0, 0, 0);
  }

  const float bn0v = b1[n0 + l15];
  const float bn1v = b1[n0 + 16 + l15];
  const float bn2v = b1[n0 + 32 + l15];
  const float bn3v = b1[n0 + 48 + l15];
  float* crow = C + (size_t)(m0 + quad * 4) * H + n0 + l15;
#pragma unroll
  for (int r = 0; r < 4; ++r) {
    crow[(size_t)r * H]      = acc0[r] + bn0v;
    crow[(size_t)r * H + 16] = acc1[r] + bn1v;
    crow[(size_t)r * H + 32] = acc2[r] + bn2v;
    crow[(size_t)r * H + 48] = acc3[r] + bn3v;
  }
}

// ---------------------------------------------------------------------------
// K3a: per-16-row-block partial column sums / sumsq of z (256 blocks).
// ---------------------------------------------------------------------------
__global__ __launch_bounds__(256) void k_colstats(
    const float* __restrict__ z, float* __restrict__ ps, float* __restrict__ pss) {
  const int blk = blockIdx.x;       // 0..255
  const int c0 = threadIdx.x * 2;
  const int r0 = blk * 16;
  float s0 = 0, s1 = 0, q0 = 0, q1 = 0;
#pragma unroll
  for (int r = 0; r < 16; ++r) {
    float2 v = *(const float2*)&z[(size_t)(r0 + r) * H + c0];
    s0 += v.x; s1 += v.y;
    q0 += v.x * v.x; q1 += v.y * v.y;
  }
  ps[blk * H + c0] = s0; ps[blk * H + c0 + 1] = s1;
  pss[blk * H + c0] = q0; pss[blk * H + c0 + 1] = q1;
}

// ---------------------------------------------------------------------------
// K3b: finalize mu/var -> fused scale/shift; zeroes loss accumulator out[0]
// (stream-ordered before k_bn_dot's atomicAdd).
// ---------------------------------------------------------------------------
__global__ __launch_bounds__(128) void k_finalize(
    const float* __restrict__ ps, const float* __restrict__ pss,
    const float* __restrict__ gamma, const float* __restrict__ beta,
    float* __restrict__ scale, float* __restrict__ shift,
    float* __restrict__ out) {
  const int c = blockIdx.x * 128 + threadIdx.x;
  if (c == 0) out[0] = 0.f;
  float s = 0, q = 0;
#pragma unroll 8
  for (int i = 0; i < 256; ++i) { s += ps[i * H + c]; q += pss[i * H + c]; }
  const float mu = s * (1.0f / NB);
  const float var = q * (1.0f / NB) - mu * mu;
  const float rstd = rsqrtf(var + EPS);
  const float sc = rstd * gamma[c];
  scale[c] = sc;
  shift[c] = beta[c] - mu * sc;
}

// ---------------------------------------------------------------------------
// K4: BN + ReLU + dot(w2) per row -> logits, BCE loss fused (per-block LDS
// reduce + one atomicAdd into out[0]).  One wave per row.
// ---------------------------------------------------------------------------
__global__ __launch_bounds__(256) void k_bn_dot(
    const float* __restrict__ z, const float* __restrict__ scale,
    const float* __restrict__ shift, const float* __restrict__ w2,
    const float* __restrict__ b2, const float* __restrict__ t,
    float* __restrict__ out) {
  const int tid = threadIdx.x;
  const int wave = tid >> 6, lane = tid & 63;
  const int b = blockIdx.x * 4 + wave;
  const float4* __restrict__ z4 = (const float4*)(z + (size_t)b * H);
  const float4* __restrict__ sc4 = (const float4*)scale;
  const float4* __restrict__ sh4 = (const float4*)shift;
  const float4* __restrict__ w24 = (const float4*)w2;
  float acc = 0.f;
#pragma unroll
  for (int i = lane; i < 128; i += 64) {
    float4 zv = z4[i], sc = sc4[i], sh = sh4[i], w = w24[i];
    float h0 = fmaxf(zv.x * sc.x + sh.x, 0.f);
    float h1 = fmaxf(zv.y * sc.y + sh.y, 0.f);
    float h2 = fmaxf(zv.z * sc.z + sh.z, 0.f);
    float h3 = fmaxf(zv.w * sc.w + sh.w, 0.f);
    acc += h0 * w.x + h1 * w.y + h2 * w.z + h3 * w.w;
  }
#pragma unroll
  for (int off = 32; off > 0; off >>= 1) acc += __shfl_down(acc, off, 64);

  __shared__ float ls[4];
  if (lane == 0) {
    const float logit = acc + b2[0];
    out[1 + b] = logit;
    const float sp = fmaxf(logit, 0.f) + log1pf(expf(-fabsf(logit)));
    ls[wave] = (sp - t[b] * logit) * (1.0f / NB);
  }
  __syncthreads();
  if (tid == 0) atomicAdd(out, ls[0] + ls[1] + ls[2] + ls[3]);
}

// ---------------------------------------------------------------------------
extern "C" void kernel_launch(void* const* d_in, const int* in_sizes, int n_in,
                              void* d_out, int out_size, void* d_ws, size_t ws_size,
                              hipStream_t stream) {
  const int*   tokens = (const int*)d_in[0];
  const int*   seg    = (const int*)d_in[1];
  const float* t      = (const float*)d_in[2];
  const float* emb    = (const float*)d_in[3];
  const float* W1     = (const float*)d_in[4];
  const float* b1     = (const float*)d_in[5];
  const float* gamma  = (const float*)d_in[6];
  const float* beta   = (const float*)d_in[7];
  const float* w2     = (const float*)d_in[8];
  const float* b2     = (const float*)d_in[9];
  float* out = (float*)d_out;

  // workspace layout (bytes)
  char* wsb = (char*)d_ws;
  half8*    embh  = (half8*)wsb;                          // 100000*512*2 = 102,400,000
  _Float16* W1h   = (_Float16*)(wsb + 102400000);         // 512*512*2 = 524,288
  half8*    bow_h = (half8*)(wsb + 102924288);            // 4096*512*2 = 4,194,304
  float*    z     = (float*)(wsb + 107118592);            // 4096*512*4 = 8,388,608
  float*    ps    = (float*)(wsb + 115507200);            // 256*512*4 = 524,288
  float*    pss   = ps + 256 * H;                         // 524,288
  float*    scale = pss + 256 * H;                        // 2,048
  float*    shift = scale + H;                            // 2,048
  int*      starts = (int*)(wsb + 116559872);             // (NB+1)*4 = 16,388

  k_convert<<<50256, 256, 0, stream>>>(emb, (h4*)embh, W1, (h4*)W1h);
  k_bounds<<<NTOK / 256, 256, 0, stream>>>(seg, starts);
  k_gather_mean<<<NB, 256, 0, stream>>>(tokens, starts, embh, bow_h);
  k_gemm_mfma<<<512, 256, 0, stream>>>((const _Float16*)bow_h, W1h, b1, z);
  k_colstats<<<256, 256, 0, stream>>>(z, ps, pss);
  k_finalize<<<4, 128, 0, stream>>>(ps, pss, gamma, beta, scale, shift, out);
  k_bn_dot<<<NB / 4, 256, 0, stream>>>(z, scale, shift, w2, b2, t, out);
}